// Round 15
// baseline (403.306 us; speedup 1.0000x reference)
//
#include <hip/hip_runtime.h>
#include <hip/hip_cooperative_groups.h>
#include <stdint.h>

namespace cg = cooperative_groups;

// Match XLA: no FMA contraction anywhere in the float math.
#pragma clang fp contract(off)

#define N_ANCH 147456
#define NBLK 576
#define NG 256
#define NBINS 4096
#define CAND_CAP 4096
#define K_POS 128u
#define RPN_BATCH 256u

// ---------------- threefry2x32 (exact JAX schedule) ----------------
struct TFOut { uint32_t x0, x1; };

__host__ __device__ constexpr TFOut threefry2x32(uint32_t k0, uint32_t k1,
                                                 uint32_t c0, uint32_t c1) {
  uint32_t ks[3] = {k0, k1, k0 ^ k1 ^ 0x1BD11BDAu};
  uint32_t x0 = c0 + ks[0];
  uint32_t x1 = c1 + ks[1];
  const uint32_t rotA[4] = {13u, 15u, 26u, 6u};
  const uint32_t rotB[4] = {17u, 29u, 16u, 24u};
#pragma unroll
  for (int g = 0; g < 5; ++g) {
#pragma unroll
    for (int r = 0; r < 4; ++r) {
      uint32_t ro = ((g & 1) == 0) ? rotA[r] : rotB[r];
      x0 += x1;
      x1 = (x1 << ro) | (x1 >> (32u - ro));
      x1 ^= x0;
    }
    x0 += ks[(g + 1) % 3];
    x1 += ks[(g + 2) % 3] + (uint32_t)(g + 1);
  }
  return TFOut{x0, x1};
}

// key(42)=[0,42]; partitionable split (verified bit-exact round 6)
constexpr TFOut SK0 = threefry2x32(0u, 42u, 0u, 0u);
constexpr TFOut SK1 = threefry2x32(0u, 42u, 0u, 1u);
constexpr uint32_t KPOS0 = SK0.x0, KPOS1 = SK0.x1;
constexpr uint32_t KNEG0 = SK1.x0, KNEG1 = SK1.x1;

__device__ __forceinline__ uint32_t rand_m23(uint32_t k0, uint32_t k1, uint32_t i) {
  TFOut o = threefry2x32(k0, k1, 0u, i);
  return (o.x0 ^ o.x1) >> 9;
}

// ---------------- anchors ----------------
__device__ const float c_base[9][4] = {
  { -84.f,  -40.f,  99.f,  55.f}, {-176.f,  -88.f, 191.f, 103.f},
  {-360.f, -184.f, 375.f, 199.f}, { -56.f,  -56.f,  71.f,  71.f},
  {-120.f, -120.f, 135.f, 135.f}, {-248.f, -248.f, 263.f, 263.f},
  { -36.f,  -80.f,  51.f,  95.f}, { -80.f, -168.f,  95.f, 183.f},
  {-168.f, -344.f, 183.f, 359.f}
};

__device__ __forceinline__ void anchor_coords(int a, float* x1, float* y1,
                                              float* x2, float* y2) {
  int b = a % 9;
  int cell = a / 9;
  float sx = (float)((cell & 127) << 4);
  float sy = (float)((cell >> 7) << 4);
  *x1 = c_base[b][0] + sx;
  *y1 = c_base[b][1] + sy;
  *x2 = c_base[b][2] + sx;
  *y2 = c_base[b][3] + sy;
}

// ws u32 layout: hp[4096] @0, hn[4096] @4096, ctrl[32] @8192 (zeroed: 8224 words),
// gl[256] @8224 (written unconditionally). cp u64[4096] @byte 33920, cn @66688.
// ctrl: 0 pos_active,1 pos_bin,2 pos_need,3 cand_pos_cnt,4 neg_active,5 neg_bin,
//       6 neg_need,7 cand_neg_cnt; u64[4]=cutoff_pos,u64[5]=cutoff_neg (0=keep-all).

__global__ __launch_bounds__(256) void k_fused(const float* __restrict__ gt,
                                               const float* __restrict__ meta,
                                               float* __restrict__ labels,
                                               float* __restrict__ targets,
                                               uint8_t* __restrict__ ws) {
  uint32_t* wsw  = (uint32_t*)ws;
  uint32_t* hp   = wsw;
  uint32_t* hn   = wsw + 4096;
  uint32_t* ctrl = wsw + 8192;
  uint32_t* gl   = wsw + 8224;
  unsigned long long* cut = (unsigned long long*)ctrl;
  unsigned long long* cp  = (unsigned long long*)(ws + 33920);
  unsigned long long* cn  = (unsigned long long*)(ws + 66688);

  __shared__ unsigned long long smem[4352];   // 34816 B union
  const int tid = threadIdx.x;
  const int bid = blockIdx.x;
  cg::grid_group grid = cg::this_grid();

  // ======== phase 0: zero hists+ctrl (blocks >=256) | gtbest per gt (blocks <256)
  if (bid >= NG) {
    int w = (bid - NG) * 256 + tid;
    if (w < 8224) wsw[w] = 0u;
  } else {
    // separable per-gt argmax (verified bit-exact rounds 9/10)
    unsigned long long* s_best = smem;        // [2][9]
    unsigned long long* s_kk   = smem + 18;   // [9]
    if (tid < 18) s_best[tid] = 0ull;
    __syncthreads();
    float4 b = ((const float4*)gt)[bid];
    const int axis = tid >> 7;
    const int p = tid & 127;
    const float shift = (float)(p << 4);
    const float lo = axis ? b.y : b.x;
    const float hi = axis ? b.w : b.z;
#pragma unroll
    for (int k = 0; k < 9; ++k) {
      float a1 = c_base[k][axis] + shift;
      float a2 = c_base[k][axis + 2] + shift;
      float ext = fminf(a2, hi) - fmaxf(a1, lo) + 1.0f;
      ext = fmaxf(ext, 0.0f);
      unsigned long long key =
          ((unsigned long long)__float_as_uint(ext) << 7)
        | (unsigned long long)(127 - p);
      atomicMax(&s_best[axis * 9 + k], key);
    }
    __syncthreads();
    if (tid < 9) {
      const int k = tid;
      unsigned long long kx = s_best[k], ky = s_best[9 + k];
      float iw = __uint_as_float((uint32_t)(kx >> 7));
      float ih = __uint_as_float((uint32_t)(ky >> 7));
      int xs = 127 - (int)(kx & 127u);
      int ys = 127 - (int)(ky & 127u);
      float inter = iw * ih;
      float area_a = (c_base[k][2] - c_base[k][0] + 1.0f) *
                     (c_base[k][3] - c_base[k][1] + 1.0f);
      float area_b = (b.z - b.x + 1.0f) * (b.w - b.y + 1.0f);
      float v = inter / (area_a + area_b - inter);
      uint32_t a = (uint32_t)((ys * 128 + xs) * 9 + k);
      s_kk[k] = ((unsigned long long)__float_as_uint(v) << 32)
              | (unsigned long long)(0xFFFFFFFFu - a);
    }
    __syncthreads();
    if (tid == 0) {
      unsigned long long best = s_kk[0];
#pragma unroll
      for (int k = 1; k < 9; ++k) if (s_kk[k] > best) best = s_kk[k];
      gl[bid] = 0xFFFFFFFFu - (uint32_t)(best & 0xFFFFFFFFull);
    }
  }
  grid.sync();  // S1: hists zeroed, gl complete

  // ======== phase B: per-anchor argmax IoU, pre-flip label, hist, targets
  float4* s_gt  = (float4*)smem;                 // 4 KB
  float*  s_area = (float*)((char*)smem + 4096); // 1 KB
  {
    float4 bb = ((const float4*)gt)[tid];
    s_gt[tid] = bb;
    s_area[tid] = (bb.z - bb.x + 1.0f) * (bb.w - bb.y + 1.0f);
  }
  __syncthreads();
  const int a = bid * 256 + tid;
  float ax1, ay1, ax2, ay2;
  anchor_coords(a, &ax1, &ay1, &ax2, &ay2);
  const float area_a = (ax2 - ax1 + 1.0f) * (ay2 - ay1 + 1.0f);
  unsigned long long c0 = 0x00000000FFFFFFFFull;  // pack(v=0, j=0)
  unsigned long long c1 = 0ull, c2 = 0ull, c3 = 0ull;
#define IOU_STEP(JJ, CH)                                                  \
  {                                                                       \
    float4 b = s_gt[(JJ)];                                                \
    float iw = fminf(ax2, b.z) - fmaxf(ax1, b.x) + 1.0f;                  \
    float ih = fminf(ay2, b.w) - fmaxf(ay1, b.y) + 1.0f;                  \
    if (iw > 0.0f && ih > 0.0f) {                                         \
      float inter = iw * ih;                                              \
      float v = inter / (area_a + s_area[(JJ)] - inter);                  \
      unsigned long long key =                                            \
          ((unsigned long long)__float_as_uint(v) << 32)                  \
        | (unsigned long long)(0xFFFFFFFFu - (uint32_t)(JJ));             \
      if (key > CH) CH = key;                                             \
    }                                                                     \
  }
  for (int j = 0; j < NG; j += 4) {
    IOU_STEP(j + 0, c0)
    IOU_STEP(j + 1, c1)
    IOU_STEP(j + 2, c2)
    IOU_STEP(j + 3, c3)
  }
#undef IOU_STEP
  if (c1 > c0) c0 = c1;
  if (c2 > c0) c0 = c2;
  if (c3 > c0) c0 = c3;
  const float best = __uint_as_float((uint32_t)(c0 >> 32));
  const int bj = (int)(0xFFFFFFFFu - (uint32_t)c0);
  float l0 = (best >= 0.7f) ? 1.0f : ((best < 0.3f) ? 0.0f : -1.0f);
  labels[a] = l0;
  if (l0 == 1.0f) {
    atomicAdd(&hp[rand_m23(KPOS0, KPOS1, (uint32_t)a) >> 11], 1u);
  } else if (l0 == 0.0f) {
    atomicAdd(&hn[rand_m23(KNEG0, KNEG1, (uint32_t)a) >> 11], 1u);
  }
  {
    float4 g = s_gt[bj];
    float ew = ax2 - ax1 + 1.0f;
    float eh = ay2 - ay1 + 1.0f;
    float ecx = ax1 + 0.5f * ew;
    float ecy = ay1 + 0.5f * eh;
    float gw = g.z - g.x + 1.0f;
    float gh = g.w - g.y + 1.0f;
    float gcx = g.x + 0.5f * gw;
    float gcy = g.y + 0.5f * gh;
    float4 t;
    t.x = (gcx - ecx) / ew;
    t.y = (gcy - ecy) / eh;
    t.z = logf(gw / ew);
    t.w = logf(gh / eh);
    ((float4*)targets)[a] = t;
  }
  grid.sync();  // S2: labels+hists complete

  // ======== phase C (block 0): apply gt-best flips + hist repair, then findbin
  if (bid == 0) {
    {
      uint32_t g = gl[tid];                     // one flip per thread
      float old = atomicExch(&labels[g], 1.0f); // dedupes shared besta
      if (old == 0.0f) {
        atomicSub(&hn[rand_m23(KNEG0, KNEG1, g) >> 11], 1u);
        atomicAdd(&hp[rand_m23(KPOS0, KPOS1, g) >> 11], 1u);
      } else if (old == -1.0f) {
        atomicAdd(&hp[rand_m23(KPOS0, KPOS1, g) >> 11], 1u);
      }
    }
    __syncthreads();
    uint32_t* s_h = (uint32_t*)smem;            // 16 KB
    uint32_t* s_c = (uint32_t*)smem + NBINS;    // 256 B
    __shared__ uint32_t s_kneg;
    // ---- positives, K = 128 ----
    for (int i = tid; i < NBINS; i += 256) s_h[i] = hp[i];
    __syncthreads();
    if (tid < 64) {
      uint32_t s = 0;
      for (int i = 0; i < 64; ++i) s += s_h[tid * 64 + i];
      s_c[tid] = s;
    }
    __syncthreads();
    if (tid == 0) {
      uint32_t total = 0;
      for (int i = 0; i < 64; ++i) total += s_c[i];
      if (total <= K_POS) {
        ctrl[0] = 0u;
        s_kneg = RPN_BATCH - total;
      } else {
        uint32_t cum = 0; int ch, bb;
        for (ch = 63; ch >= 0; --ch) { if (cum + s_c[ch] >= K_POS) break; cum += s_c[ch]; }
        for (bb = ch * 64 + 63; bb >= ch * 64; --bb) { if (cum + s_h[bb] >= K_POS) break; cum += s_h[bb]; }
        ctrl[0] = 1u; ctrl[1] = (uint32_t)bb; ctrl[2] = K_POS - cum;
        s_kneg = RPN_BATCH - K_POS;
      }
    }
    __syncthreads();
    // ---- negatives, K = s_kneg ----
    for (int i = tid; i < NBINS; i += 256) s_h[i] = hn[i];
    __syncthreads();
    if (tid < 64) {
      uint32_t s = 0;
      for (int i = 0; i < 64; ++i) s += s_h[tid * 64 + i];
      s_c[tid] = s;
    }
    __syncthreads();
    if (tid == 0) {
      uint32_t total = 0;
      for (int i = 0; i < 64; ++i) total += s_c[i];
      uint32_t K = s_kneg;
      if (K == 0u) {
        ctrl[4] = 0u;
        cut[5] = ~0ull;                          // drop all negatives
      } else if (total <= K) {
        ctrl[4] = 0u;                            // keep all
      } else {
        uint32_t cum = 0; int ch, bb;
        for (ch = 63; ch >= 0; --ch) { if (cum + s_c[ch] >= K) break; cum += s_c[ch]; }
        for (bb = ch * 64 + 63; bb >= ch * 64; --bb) { if (cum + s_h[bb] >= K) break; cum += s_h[bb]; }
        ctrl[4] = 1u; ctrl[5] = (uint32_t)bb; ctrl[6] = K - cum;
      }
    }
  }
  grid.sync();  // S3: flips + ctrl bins ready

  // ======== phase D: collect threshold-bin candidates (post-flip labels)
  // atomic load bypasses this CU's (possibly stale) L1 for the flipped entries
  const float l = __hip_atomic_load(&labels[a], __ATOMIC_RELAXED, __HIP_MEMORY_SCOPE_AGENT);
  if (l == 1.0f) {
    if (ctrl[0]) {
      uint32_t m = rand_m23(KPOS0, KPOS1, (uint32_t)a);
      if ((m >> 11) == ctrl[1]) {
        uint32_t i = atomicAdd(&ctrl[3], 1u);
        if (i < CAND_CAP)
          cp[i] = ((unsigned long long)m << 32) | (unsigned long long)(0xFFFFFFFFu - (uint32_t)a);
      }
    }
  } else if (l == 0.0f) {
    if (ctrl[4]) {
      uint32_t m = rand_m23(KNEG0, KNEG1, (uint32_t)a);
      if ((m >> 11) == ctrl[5]) {
        uint32_t i = atomicAdd(&ctrl[7], 1u);
        if (i < CAND_CAP)
          cn[i] = ((unsigned long long)m << 32) | (unsigned long long)(0xFFFFFFFFu - (uint32_t)a);
      }
    }
  }
  grid.sync();  // S4: candidates complete

  // ======== phase E (block 0): exact cutoff keys among candidates
  if (bid == 0) {
    unsigned long long* s_k = smem;         // 32 KB
    unsigned long long* s_m = smem + CAND_CAP;  // 2 KB
    for (int phase = 0; phase < 2; ++phase) {
      uint32_t active = __hip_atomic_load(&ctrl[phase ? 4 : 0], __ATOMIC_RELAXED, __HIP_MEMORY_SCOPE_AGENT);
      if (!active) continue;                // uniform across block
      uint32_t c = __hip_atomic_load(&ctrl[phase ? 7 : 3], __ATOMIC_RELAXED, __HIP_MEMORY_SCOPE_AGENT);
      if (c > CAND_CAP) c = CAND_CAP;
      uint32_t need = __hip_atomic_load(&ctrl[phase ? 6 : 2], __ATOMIC_RELAXED, __HIP_MEMORY_SCOPE_AGENT);
      const unsigned long long* cand = phase ? cn : cp;
      for (uint32_t i = tid; i < c; i += 256) s_k[i] = cand[i];
      __syncthreads();
      unsigned long long mymin = ~0ull;
      for (uint32_t i = tid; i < c; i += 256) {
        unsigned long long k = s_k[i];
        uint32_t r = 0;
        for (uint32_t j = 0; j < c; ++j) r += (s_k[j] > k) ? 1u : 0u;
        if (r < need && k < mymin) mymin = k;  // kept candidate, min key
      }
      s_m[tid] = mymin;
      __syncthreads();
      for (int s = 128; s > 0; s >>= 1) {
        if (tid < s) {
          unsigned long long o = s_m[tid + s];
          if (o < s_m[tid]) s_m[tid] = o;
        }
        __syncthreads();
      }
      if (tid == 0)
        __hip_atomic_store(&cut[4 + phase], s_m[0], __ATOMIC_RELAXED, __HIP_MEMORY_SCOPE_AGENT);
      __syncthreads();
    }
  }
  grid.sync();  // S5: cutoffs ready

  // ======== phase F: apply subsample drops + inside mask
  float lf = l;
  if (lf == 1.0f) {
    unsigned long long key = ((unsigned long long)rand_m23(KPOS0, KPOS1, (uint32_t)a) << 32)
                           | (unsigned long long)(0xFFFFFFFFu - (uint32_t)a);
    if (key < __hip_atomic_load(&cut[4], __ATOMIC_RELAXED, __HIP_MEMORY_SCOPE_AGENT)) lf = -1.0f;
  } else if (lf == 0.0f) {
    unsigned long long key = ((unsigned long long)rand_m23(KNEG0, KNEG1, (uint32_t)a) << 32)
                           | (unsigned long long)(0xFFFFFFFFu - (uint32_t)a);
    if (key < __hip_atomic_load(&cut[5], __ATOMIC_RELAXED, __HIP_MEMORY_SCOPE_AGENT)) lf = -1.0f;
  }
  {
    float hh = meta[0], ww = meta[1];
    bool inside = (ax1 >= 0.0f) && (ay1 >= 0.0f) && (ax2 < ww) && (ay2 < hh);
    if (!inside) lf = -1.0f;
  }
  labels[a] = lf;
}

// ---------------- launch ----------------
extern "C" void kernel_launch(void* const* d_in, const int* in_sizes, int n_in,
                              void* d_out, int out_size, void* d_ws, size_t ws_size,
                              hipStream_t stream) {
  (void)in_sizes; (void)n_in; (void)out_size; (void)ws_size;
  const float* gt   = (const float*)d_in[1];
  const float* meta = (const float*)d_in[2];
  float* labels  = (float*)d_out;
  float* targets = labels + N_ANCH;
  uint8_t* ws = (uint8_t*)d_ws;

  void* args[] = {(void*)&gt, (void*)&meta, (void*)&labels, (void*)&targets, (void*)&ws};
  hipLaunchCooperativeKernel((const void*)k_fused, dim3(NBLK), dim3(256),
                             args, 0, stream);
}